// Round 5
// baseline (171.350 us; speedup 1.0000x reference)
//
#include <hip/hip_runtime.h>
#include <math.h>

// Problem constants (from reference): eps_t, y_t are (256, 24, 4096) f32.
#define BATCH_SZ   256
#define D_EVENT    (24 * 4096)                  // 98304
#define N_TOTAL    (BATCH_SZ * D_EVENT)         // 25,165,824

#define BLOCK      256
#define GRID       4096
#define STRIDE     (GRID * BLOCK)               // 1,048,576 threads
#define N4         (N_TOTAL / 4)                // 6,291,456 float4
#define ITERS      (N4 / STRIDE)                // 6, exact — no remainder
#define GROUP      3                            // 6 float4 loads in flight

// Fused: masked sum-of-squares reduction + last-block finalize.
// Main loop identical to R4 (moderate MLP x high TLP — R3 showed deep
// load groups regress). Last arriving block (device-scope atomic counter)
// reduces the 4096 partials and computes the closed-form loss, removing
// the separate finalize kernel node (~4-5 us of graph/dispatch overhead).
__global__ void __launch_bounds__(BLOCK)
mgd_fused_kernel(const float4* __restrict__ eps,
                 const float4* __restrict__ y,
                 const float* __restrict__ sigma,
                 float* __restrict__ partials,
                 unsigned int* __restrict__ counter,
                 float* __restrict__ out) {
    int tid = blockIdx.x * BLOCK + threadIdx.x;
    float s0 = 0.0f, s1 = 0.0f, s2 = 0.0f, s3 = 0.0f;

    #pragma unroll
    for (int k = 0; k < ITERS; k += GROUP) {
        float4 e[GROUP], g[GROUP];
        #pragma unroll
        for (int j = 0; j < GROUP; ++j) e[j] = eps[tid + (k + j) * STRIDE];
        #pragma unroll
        for (int j = 0; j < GROUP; ++j) g[j] = y  [tid + (k + j) * STRIDE];
        #pragma unroll
        for (int j = 0; j < GROUP; ++j) {
            float m;
            m = (g[j].x != 0.0f) ? e[j].x : 0.0f; s0 = fmaf(m, m, s0);
            m = (g[j].y != 0.0f) ? e[j].y : 0.0f; s1 = fmaf(m, m, s1);
            m = (g[j].z != 0.0f) ? e[j].z : 0.0f; s2 = fmaf(m, m, s2);
            m = (g[j].w != 0.0f) ? e[j].w : 0.0f; s3 = fmaf(m, m, s3);
        }
    }
    float sum = (s0 + s1) + (s2 + s3);

    // Wave-64 shuffle reduction.
    #pragma unroll
    for (int off = 32; off > 0; off >>= 1)
        sum += __shfl_down(sum, off, 64);
    __shared__ float lds[BLOCK / 64];
    __shared__ int is_last;
    int lane = threadIdx.x & 63;
    int wave = threadIdx.x >> 6;
    if (lane == 0) lds[wave] = sum;
    __syncthreads();
    if (threadIdx.x == 0) {
        partials[blockIdx.x] = (lds[0] + lds[1]) + (lds[2] + lds[3]);
        __threadfence();                         // partial visible device-wide
        unsigned int prev = atomicAdd(counter, 1u);   // device-scope
        is_last = (prev == GRID - 1);
    }
    __syncthreads();

    if (is_last) {
        __threadfence();                         // acquire: see all partials
        const float4* p4 = (const float4*)partials;
        float fsum = 0.0f;
        #pragma unroll
        for (int k = 0; k < GRID / 4 / BLOCK; ++k) {   // 4 iters
            float4 p = p4[threadIdx.x + k * BLOCK];
            fsum += (p.x + p.y) + (p.z + p.w);
        }
        #pragma unroll
        for (int off = 32; off > 0; off >>= 1)
            fsum += __shfl_down(fsum, off, 64);
        if (lane == 0) lds[wave] = fsum;
        __syncthreads();
        if (threadIdx.x == 0) {
            float acc = (lds[0] + lds[1]) + (lds[2] + lds[3]);
            float sg = sigma[0];
            float s = fmaxf(sg, 0.0f) + log1pf(expf(-fabsf(sg)));  // softplus
            const float LOG_2PI = 1.8378770664093453f;
            float quad_mean = acc / ((float)BATCH_SZ * s);
            out[0] = 0.5f * (quad_mean + (float)D_EVENT * (LOG_2PI + logf(s)));
        }
    }
}

extern "C" void kernel_launch(void* const* d_in, const int* in_sizes, int n_in,
                              void* d_out, int out_size, void* d_ws, size_t ws_size,
                              hipStream_t stream) {
    const float4* eps   = (const float4*)d_in[0];
    const float4* y     = (const float4*)d_in[1];
    const float*  sigma = (const float*)d_in[2];
    float* out      = (float*)d_out;
    float* partials = (float*)d_ws;                       // 4096 floats
    unsigned int* counter = (unsigned int*)((char*)d_ws + GRID * sizeof(float));

    // Counter must be 0 at every call (d_ws poisoned once, never restored).
    hipMemsetAsync(counter, 0, sizeof(unsigned int), stream);

    mgd_fused_kernel<<<GRID, BLOCK, 0, stream>>>(eps, y, sigma,
                                                 partials, counter, out);
}

// Round 6
// 37.955 us; speedup vs baseline: 4.5145x; 4.5145x over previous
//
#include <hip/hip_runtime.h>
#include <math.h>

// Problem constants (from reference): eps_t, y_t are (256, 24, 4096) f32.
#define BATCH_SZ   256
#define D_EVENT    (24 * 4096)                  // 98304
#define N_TOTAL    (BATCH_SZ * D_EVENT)         // 25,165,824

#define BLOCK      256
#define GRID       8192
#define STRIDE     (GRID * BLOCK)               // 2,097,152 threads
#define N4         (N_TOTAL / 4)                // 6,291,456 float4
#define ITERS      (N4 / STRIDE)                // 3, exact — no remainder
#define GROUP      3                            // 6 float4 loads in flight

// R5 lesson: fused last-block finalize with __threadfence() regressed 4.5x —
// device-scope release fence = L2 writeback per block on non-coherent
// per-XCD L2s. Reverted to the two-kernel R4 structure (no fences, no
// atomics, deterministic partial writes). This round's experiment:
// GRID 4096->8192 (ITERS 6->3) for finer tail load-balance.
__global__ void __launch_bounds__(BLOCK)
mgd_reduce_kernel(const float4* __restrict__ eps,
                  const float4* __restrict__ y,
                  float* __restrict__ partials) {
    int tid = blockIdx.x * BLOCK + threadIdx.x;
    float s0 = 0.0f, s1 = 0.0f, s2 = 0.0f, s3 = 0.0f;

    // Single group: issue all 6 loads before any use.
    float4 e[GROUP], g[GROUP];
    #pragma unroll
    for (int j = 0; j < GROUP; ++j) e[j] = eps[tid + j * STRIDE];
    #pragma unroll
    for (int j = 0; j < GROUP; ++j) g[j] = y  [tid + j * STRIDE];
    #pragma unroll
    for (int j = 0; j < GROUP; ++j) {
        float m;
        m = (g[j].x != 0.0f) ? e[j].x : 0.0f; s0 = fmaf(m, m, s0);
        m = (g[j].y != 0.0f) ? e[j].y : 0.0f; s1 = fmaf(m, m, s1);
        m = (g[j].z != 0.0f) ? e[j].z : 0.0f; s2 = fmaf(m, m, s2);
        m = (g[j].w != 0.0f) ? e[j].w : 0.0f; s3 = fmaf(m, m, s3);
    }
    float sum = (s0 + s1) + (s2 + s3);

    // Wave-64 shuffle reduction.
    #pragma unroll
    for (int off = 32; off > 0; off >>= 1)
        sum += __shfl_down(sum, off, 64);
    __shared__ float lds[BLOCK / 64];
    int lane = threadIdx.x & 63;
    int wave = threadIdx.x >> 6;
    if (lane == 0) lds[wave] = sum;
    __syncthreads();
    if (threadIdx.x == 0)
        partials[blockIdx.x] = (lds[0] + lds[1]) + (lds[2] + lds[3]);
}

// One 256-thread block: reduce 8192 partials + closed-form loss.
__global__ void __launch_bounds__(BLOCK)
mgd_finalize_kernel(const float* __restrict__ partials,
                    const float* __restrict__ sigma,
                    float* __restrict__ out) {
    const float4* p4 = (const float4*)partials;
    float sum = 0.0f;
    #pragma unroll
    for (int k = 0; k < GRID / 4 / BLOCK; ++k) {          // 8 iters
        float4 p = p4[threadIdx.x + k * BLOCK];
        sum += (p.x + p.y) + (p.z + p.w);
    }
    #pragma unroll
    for (int off = 32; off > 0; off >>= 1)
        sum += __shfl_down(sum, off, 64);
    __shared__ float lds[BLOCK / 64];
    int lane = threadIdx.x & 63;
    int wave = threadIdx.x >> 6;
    if (lane == 0) lds[wave] = sum;
    __syncthreads();
    if (threadIdx.x == 0) {
        float acc = (lds[0] + lds[1]) + (lds[2] + lds[3]);
        float sg = sigma[0];
        float s = fmaxf(sg, 0.0f) + log1pf(expf(-fabsf(sg)));  // softplus
        const float LOG_2PI = 1.8378770664093453f;
        float quad_mean = acc / ((float)BATCH_SZ * s);
        out[0] = 0.5f * (quad_mean + (float)D_EVENT * (LOG_2PI + logf(s)));
    }
}

extern "C" void kernel_launch(void* const* d_in, const int* in_sizes, int n_in,
                              void* d_out, int out_size, void* d_ws, size_t ws_size,
                              hipStream_t stream) {
    const float4* eps   = (const float4*)d_in[0];
    const float4* y     = (const float4*)d_in[1];
    const float*  sigma = (const float*)d_in[2];
    float* out      = (float*)d_out;
    float* partials = (float*)d_ws;            // 8192 floats = 32 KB scratch

    mgd_reduce_kernel  <<<GRID, BLOCK, 0, stream>>>(eps, y, partials);
    mgd_finalize_kernel<<<1,    BLOCK, 0, stream>>>(partials, sigma, out);
}